// Round 3
// baseline (268.898 us; speedup 1.0000x reference)
//
#include <hip/hip_runtime.h>
#include <math.h>

// NoisyTopkRouter, round 3: barrier-free K-loop.
//   C = A*W^T via bf16x2 split (Ah*Wh + Ah*Wl + Al*Wh), 16x16x32 bf16 MFMA.
// prepack_w: W fp32 -> hi/lo bf16 planes in d_ws, MFMA B-frag order (L2-resident).
// router_mfma: each wave = 16 tokens x 64 cols (route cols wn*32+{0,16} AND the
//   matching noise cols) -> route/noise fuse is lane-local. A frags loaded
//   straight from global (fp32, 2x float4/lane), converted in-register; no LDS
//   and no __syncthreads in the K-loop. Grid 1024 x 256thr -> 4 waves/SIMD.

#define T_TOKENS 32768
#define D_MODEL  1024
#define NE       64
#define NCOL     128
#define M_TILE   32
#define NCHUNK   (D_MODEL / 32)        // 32 chunks of K=32
#define CS_LD    68                    // Cs[token][expert] stride (2-way banks = free)
#define OUT_IDX_BASE ((size_t)T_TOKENS * NE)
#define W_ELEMS  (NCOL * D_MODEL)

typedef short  bf16x8  __attribute__((ext_vector_type(8)));
typedef float  floatx4 __attribute__((ext_vector_type(4)));

__device__ __forceinline__ unsigned short f32_to_bf16_rne(float x) {
    unsigned u = __float_as_uint(x);
    unsigned r = u + 0x7fffu + ((u >> 16) & 1u);
    return (unsigned short)(r >> 16);
}
__device__ __forceinline__ float bf16_bits_to_f32(unsigned short h) {
    return __uint_as_float(((unsigned)h) << 16);
}
__device__ __forceinline__ int4 pack8(const unsigned short* h) {
    int4 r;
    r.x = (int)((unsigned)h[0] | ((unsigned)h[1] << 16));
    r.y = (int)((unsigned)h[2] | ((unsigned)h[3] << 16));
    r.z = (int)((unsigned)h[4] | ((unsigned)h[5] << 16));
    r.w = (int)((unsigned)h[6] | ((unsigned)h[7] << 16));
    return r;
}
__device__ __forceinline__ float softplus_f(float x) {
    return fmaxf(x, 0.f) + log1pf(expf(-fabsf(x)));
}

// ---------------- prepack: W -> hi/lo bf16 in B-frag order ----------------
// elem index = ((ntile*128 + kgrp)*16 + n16)*8 + j ; value = W[ntile*16+n16][kgrp*8+j]
__global__ __launch_bounds__(256) void prepack_w(
    const float* __restrict__ Wr, const float* __restrict__ Wn,
    short* __restrict__ Bh, short* __restrict__ Bl)
{
    int g   = blockIdx.x * 256 + threadIdx.x;   // 16384 groups of 8 k
    int n   = g & 15;
    int kg  = (g >> 4) & 127;
    int t2  = g >> 11;
    int col = t2 * 16 + n;
    const float* src = (col < NE ? Wr + (size_t)col * D_MODEL
                                 : Wn + (size_t)(col - NE) * D_MODEL) + kg * 8;
    float4 a = *(const float4*)src;
    float4 b = *(const float4*)(src + 4);
    float v[8] = {a.x, a.y, a.z, a.w, b.x, b.y, b.z, b.w};
    unsigned short h[8], l[8];
    #pragma unroll
    for (int j = 0; j < 8; ++j) {
        h[j] = f32_to_bf16_rne(v[j]);
        l[j] = f32_to_bf16_rne(v[j] - bf16_bits_to_f32(h[j]));
    }
    *(int4*)(Bh + (size_t)g * 8) = pack8(h);
    *(int4*)(Bl + (size_t)g * 8) = pack8(l);
}

// ---------------- main fused kernel ----------------
__global__ __launch_bounds__(256, 4) void router_mfma(
    const float* __restrict__ A,      // [T, D]
    const float* __restrict__ noise,  // [T, NE]
    const float* __restrict__ br,     // [NE]
    const float* __restrict__ bn,     // [NE]
    const short* __restrict__ Bh,
    const short* __restrict__ Bl,
    float* __restrict__ out)
{
    __shared__ float Cs[M_TILE * CS_LD];     // noisy logits [token][expert]
    __shared__ float s_p1[M_TILE], s_p2[M_TILE];
    __shared__ int   s_e1[M_TILE], s_e2[M_TILE];

    const int tid  = threadIdx.x;
    const int lane = tid & 63;
    const int wid  = tid >> 6;
    const int wm   = wid & 1;     // token half: rows wm*16..+15
    const int wn   = wid >> 1;    // col group: route cols wn*32..+31 (+64 noise)
    const int n16  = lane & 15;
    const int quad = lane >> 4;
    const int m0   = blockIdx.x * M_TILE;

    // A: lane's MFMA A-frag = row (m0+wm*16+n16), k = kc*32 + quad*8 .. +7
    const float* pA = A + (size_t)(m0 + wm * 16 + n16) * D_MODEL + quad * 8;

    // B frag bases: f=0,1 -> route ntiles wn*2+f ; f=2,3 -> noise ntiles 4+wn*2+(f-2)
    int bBase[4];
    #pragma unroll
    for (int f = 0; f < 4; ++f) {
        int ntile = (f < 2) ? (wn * 2 + f) : (4 + wn * 2 + (f - 2));
        bBase[f] = ((ntile * 128 + quad) * 16 + n16) * 8;
    }

    floatx4 acc[4];
    #pragma unroll
    for (int f = 0; f < 4; ++f) acc[f] = (floatx4)0.f;

    // A register prefetch pipeline, depth 2
    float4 aC0 = *(const float4*)(pA);
    float4 aC1 = *(const float4*)(pA + 4);
    float4 aN0 = *(const float4*)(pA + 32);
    float4 aN1 = *(const float4*)(pA + 36);

    for (int kc = 0; kc < NCHUNK; ++kc) {
        // issue A load for kc+2 first (longest latency)
        float4 aF0, aF1;
        if (kc + 2 < NCHUNK) {
            aF0 = *(const float4*)(pA + (kc + 2) * 32);
            aF1 = *(const float4*)(pA + (kc + 2) * 32 + 4);
        }
        // B frags for this chunk (L1/L2-resident packed planes)
        bf16x8 bh[4], bl[4];
        #pragma unroll
        for (int f = 0; f < 4; ++f) {
            size_t o = (size_t)bBase[f] + (size_t)kc * 512;
            bh[f] = *(const bf16x8*)(Bh + o);
            bl[f] = *(const bf16x8*)(Bl + o);
        }
        // convert current A chunk to hi/lo bf16 frags (VALU, overlaps loads)
        float v[8] = {aC0.x, aC0.y, aC0.z, aC0.w, aC1.x, aC1.y, aC1.z, aC1.w};
        bf16x8 afh, afl;
        #pragma unroll
        for (int j = 0; j < 8; ++j) {
            unsigned short h = f32_to_bf16_rne(v[j]);
            afh[j] = (short)h;
            afl[j] = (short)f32_to_bf16_rne(v[j] - bf16_bits_to_f32(h));
        }
        // 12 MFMAs
        #pragma unroll
        for (int f = 0; f < 4; ++f) {
            acc[f] = __builtin_amdgcn_mfma_f32_16x16x32_bf16(afh, bh[f], acc[f], 0, 0, 0);
            acc[f] = __builtin_amdgcn_mfma_f32_16x16x32_bf16(afh, bl[f], acc[f], 0, 0, 0);
            acc[f] = __builtin_amdgcn_mfma_f32_16x16x32_bf16(afl, bh[f], acc[f], 0, 0, 0);
        }
        // rotate A pipeline
        aC0 = aN0; aC1 = aN1; aN0 = aF0; aN1 = aF1;
    }

    // ---- lane-local fuse: noisy = route + noise * softplus(noise_logit) ----
    // D layout: col = lane&15 within frag, row = quad*4 + r
    #pragma unroll
    for (int nfi = 0; nfi < 2; ++nfi) {
        int e = wn * 32 + nfi * 16 + n16;
        float brv = br[e], bnv = bn[e];
        #pragma unroll
        for (int r = 0; r < 4; ++r) {
            int t = wm * 16 + quad * 4 + r;
            float nz    = noise[(size_t)(m0 + t) * NE + e];
            float route = acc[nfi][r]     + brv;
            float nl    = acc[2 + nfi][r] + bnv;
            Cs[t * CS_LD + e] = fmaf(nz, softplus_f(nl), route);
        }
    }
    __syncthreads();

    // ---- top-2 + softmax (one thread per token; in-order scan = stable ties) ----
    if (tid < M_TILE) {
        const int t = tid;
        float v1 = -INFINITY, v2 = -INFINITY;
        int e1 = 0, e2 = 0;
        #pragma unroll 8
        for (int e = 0; e < NE; ++e) {
            float v = Cs[t * CS_LD + e];
            if (v > v1) { v2 = v1; e2 = e1; v1 = v; e1 = e; }
            else if (v > v2) { v2 = v; e2 = e; }
        }
        float ex = expf(v2 - v1);
        float denom = 1.f + ex;
        s_p1[t] = 1.f / denom;
        s_p2[t] = ex / denom;
        s_e1[t] = e1;
        s_e2[t] = e2;
        float2 iv = make_float2((float)e1, (float)e2);
        *(float2*)(out + OUT_IDX_BASE + (size_t)(m0 + t) * 2) = iv;
    }
    __syncthreads();

    // ---- coalesced scatter of router_output [32 tokens x 64 experts] ----
    #pragma unroll
    for (int i = 0; i < 2; ++i) {
        int gi = i * 256 + tid;       // 0..511 float4s
        int t  = gi >> 4;
        int e0 = (gi & 15) * 4;
        float p1 = s_p1[t], p2 = s_p2[t];
        int   e1 = s_e1[t], e2 = s_e2[t];
        float4 v;
        v.x = (e0 + 0 == e1) ? p1 : ((e0 + 0 == e2) ? p2 : 0.f);
        v.y = (e0 + 1 == e1) ? p1 : ((e0 + 1 == e2) ? p2 : 0.f);
        v.z = (e0 + 2 == e1) ? p1 : ((e0 + 2 == e2) ? p2 : 0.f);
        v.w = (e0 + 3 == e1) ? p1 : ((e0 + 3 == e2) ? p2 : 0.f);
        *(float4*)(out + (size_t)(m0 + t) * NE + e0) = v;
    }
}

extern "C" void kernel_launch(void* const* d_in, const int* in_sizes, int n_in,
                              void* d_out, int out_size, void* d_ws, size_t ws_size,
                              hipStream_t stream) {
    const float* A     = (const float*)d_in[0];
    const float* noise = (const float*)d_in[1];
    const float* Wr    = (const float*)d_in[2];
    const float* br    = (const float*)d_in[3];
    const float* Wn    = (const float*)d_in[4];
    const float* bn    = (const float*)d_in[5];
    float* out = (float*)d_out;

    short* Bh = (short*)d_ws;
    short* Bl = Bh + W_ELEMS;

    prepack_w<<<dim3(W_ELEMS / 8 / 256), dim3(256), 0, stream>>>(Wr, Wn, Bh, Bl);
    router_mfma<<<dim3(T_TOKENS / M_TILE), dim3(256), 0, stream>>>(A, noise, br, bn, Bh, Bl, out);
}

// Round 4
// 232.612 us; speedup vs baseline: 1.1560x; 1.1560x over previous
//
#include <hip/hip_runtime.h>
#include <math.h>

// NoisyTopkRouter round 4: bf16x2-split MFMA (Ah*Wh + Ah*Wl + Al*Wh).
// - A: fp32 -> hi/lo bf16 converted ONCE per block into double-buffered LDS
//   (1 barrier/chunk), raw-A register pipeline depth 2 hides HBM latency.
// - B: prepacked frag-order planes in d_ws (L1/L2-resident), register-
//   prefetched one chunk ahead.
// - Wave w owns route ntile w + noise ntile w+4 -> route/noise fuse is
//   lane-local; Cs is only [32 tokens x 68].
// - M_TILE=32 -> grid 1024, ~17 KB LDS -> 4 blocks/CU (4 waves/SIMD).

#define T_TOKENS 32768
#define D_MODEL  1024
#define NE       64
#define NCOL     128
#define M_TILE   32
#define NCHUNK   (D_MODEL / 32)
#define CS_LD    68
#define OUT_IDX_BASE ((size_t)T_TOKENS * NE)
#define W_ELEMS  (NCOL * D_MODEL)

typedef short  bf16x8  __attribute__((ext_vector_type(8)));
typedef float  floatx4 __attribute__((ext_vector_type(4)));

__device__ __forceinline__ unsigned short f32_to_bf16_rne(float x) {
    unsigned u = __float_as_uint(x);
    unsigned r = u + 0x7fffu + ((u >> 16) & 1u);
    return (unsigned short)(r >> 16);
}
__device__ __forceinline__ float bf16_bits_to_f32(unsigned short h) {
    return __uint_as_float(((unsigned)h) << 16);
}
__device__ __forceinline__ float softplus_f(float x) {
    return fmaxf(x, 0.f) + log1pf(expf(-fabsf(x)));
}

// ---------------- prepack: W -> hi/lo bf16 in B-frag order ----------------
// elem index = ((ntile*128 + kgrp)*16 + n16)*8 + j ; value = W[ntile*16+n16][kgrp*8+j]
__global__ __launch_bounds__(256) void prepack_w(
    const float* __restrict__ Wr, const float* __restrict__ Wn,
    short* __restrict__ Bh, short* __restrict__ Bl)
{
    int g   = blockIdx.x * 256 + threadIdx.x;   // 16384 groups of 8 k
    int n   = g & 15;
    int kg  = (g >> 4) & 127;
    int t2  = g >> 11;
    int col = t2 * 16 + n;
    const float* src = (col < NE ? Wr + (size_t)col * D_MODEL
                                 : Wn + (size_t)(col - NE) * D_MODEL) + kg * 8;
    float4 a = *(const float4*)src;
    float4 b = *(const float4*)(src + 4);
    float v[8] = {a.x, a.y, a.z, a.w, b.x, b.y, b.z, b.w};
    unsigned short h[8], l[8];
    #pragma unroll
    for (int j = 0; j < 8; ++j) {
        h[j] = f32_to_bf16_rne(v[j]);
        l[j] = f32_to_bf16_rne(v[j] - bf16_bits_to_f32(h[j]));
    }
    int4 hp, lp;
    hp.x = (int)((unsigned)h[0] | ((unsigned)h[1] << 16));
    hp.y = (int)((unsigned)h[2] | ((unsigned)h[3] << 16));
    hp.z = (int)((unsigned)h[4] | ((unsigned)h[5] << 16));
    hp.w = (int)((unsigned)h[6] | ((unsigned)h[7] << 16));
    lp.x = (int)((unsigned)l[0] | ((unsigned)l[1] << 16));
    lp.y = (int)((unsigned)l[2] | ((unsigned)l[3] << 16));
    lp.z = (int)((unsigned)l[4] | ((unsigned)l[5] << 16));
    lp.w = (int)((unsigned)l[6] | ((unsigned)l[7] << 16));
    *(int4*)(Bh + (size_t)g * 8) = hp;
    *(int4*)(Bl + (size_t)g * 8) = lp;
}

// ---------------- main fused kernel ----------------
__global__ __launch_bounds__(256, 4) void router_mfma(
    const float* __restrict__ A,      // [T, D]
    const float* __restrict__ noise,  // [T, NE]
    const float* __restrict__ br,     // [NE]
    const float* __restrict__ bn,     // [NE]
    const short* __restrict__ Bh,
    const short* __restrict__ Bl,
    float* __restrict__ out)
{
    // A chunk hi/lo, double-buffered, frag order: elem (quad*32 + m)*8 + j
    __shared__ __align__(16) short Ah[2][M_TILE * 32];
    __shared__ __align__(16) short Al[2][M_TILE * 32];
    __shared__ float Cs[M_TILE * CS_LD];
    __shared__ float s_p1[M_TILE], s_p2[M_TILE];
    __shared__ int   s_e1[M_TILE], s_e2[M_TILE];

    const int tid  = threadIdx.x;
    const int lane = tid & 63;
    const int wid  = tid >> 6;   // wave: route ntile wid, noise ntile wid+4
    const int n16  = lane & 15;
    const int quad = lane >> 4;
    const int m0   = blockIdx.x * M_TILE;

    // ---- staging mapping: tid -> (token ms, k-float4 kq) ----
    const int ms = tid >> 3;          // 0..31
    const int kq = tid & 7;           // 0..7  (k offset kq*4 within chunk)
    const float* pA = A + (size_t)(m0 + ms) * D_MODEL + kq * 4;
    const int sBase = ((kq >> 1) * M_TILE + ms) * 8 + (kq & 1) * 4; // LDS elem base (8B-aligned)

    // ---- B frag bases ----
    const int bBaseR = ((wid * 128 + quad) * 16 + n16) * 8;        // route ntile wid
    const int bBaseN = (((4 + wid) * 128 + quad) * 16 + n16) * 8;  // noise ntile wid+4

    floatx4 acc[2][2];   // [m-frag][route|noise]
    #pragma unroll
    for (int i = 0; i < 2; ++i) { acc[i][0] = (floatx4)0.f; acc[i][1] = (floatx4)0.f; }

#define CONVERT_STORE(buf_, f4_) do {                                       \
        float v_[4] = {(f4_).x, (f4_).y, (f4_).z, (f4_).w};                  \
        unsigned short h_[4], l_[4];                                         \
        _Pragma("unroll")                                                    \
        for (int j_ = 0; j_ < 4; ++j_) {                                     \
            h_[j_] = f32_to_bf16_rne(v_[j_]);                                \
            l_[j_] = f32_to_bf16_rne(v_[j_] - bf16_bits_to_f32(h_[j_]));     \
        }                                                                    \
        int2 hp_, lp_;                                                       \
        hp_.x = (int)((unsigned)h_[0] | ((unsigned)h_[1] << 16));            \
        hp_.y = (int)((unsigned)h_[2] | ((unsigned)h_[3] << 16));            \
        lp_.x = (int)((unsigned)l_[0] | ((unsigned)l_[1] << 16));            \
        lp_.y = (int)((unsigned)l_[2] | ((unsigned)l_[3] << 16));            \
        *(int2*)&Ah[(buf_)][sBase] = hp_;                                    \
        *(int2*)&Al[(buf_)][sBase] = lp_;                                    \
    } while (0)

    // ---- prologue: stage chunk 0; preload B(0); A raw pipeline depth 2 ----
    {
        float4 a0 = *(const float4*)pA;
        CONVERT_STORE(0, a0);
    }
    bf16x8 bhR, blR, bhN, blN;
    bhR = *(const bf16x8*)(Bh + bBaseR);
    blR = *(const bf16x8*)(Bl + bBaseR);
    bhN = *(const bf16x8*)(Bh + bBaseN);
    blN = *(const bf16x8*)(Bl + bBaseN);
    float4 aP1 = *(const float4*)(pA + 32);   // raw A for chunk 1
    __syncthreads();

    for (int kc = 0; kc < NCHUNK; ++kc) {
        const int cur = kc & 1, nxt = cur ^ 1;

        // issue longest-latency loads first: raw A for kc+2
        float4 aP2;
        if (kc + 2 < NCHUNK)
            aP2 = *(const float4*)(pA + (kc + 2) * 32);

        // B for kc+1 (L1/L2-resident)
        bf16x8 bhRn, blRn, bhNn, blNn;
        if (kc + 1 < NCHUNK) {
            int o = (kc + 1) * 512;
            bhRn = *(const bf16x8*)(Bh + bBaseR + o);
            blRn = *(const bf16x8*)(Bl + bBaseR + o);
            bhNn = *(const bf16x8*)(Bh + bBaseN + o);
            blNn = *(const bf16x8*)(Bl + bBaseN + o);
        }

        // A frags from LDS (conflict-free 16B/lane)
        bf16x8 afh[2], afl[2];
        #pragma unroll
        for (int mf = 0; mf < 2; ++mf) {
            int g = (quad * M_TILE + mf * 16 + n16) * 8;
            afh[mf] = *(const bf16x8*)&Ah[cur][g];
            afl[mf] = *(const bf16x8*)&Al[cur][g];
        }

        // 12 MFMAs
        #pragma unroll
        for (int mf = 0; mf < 2; ++mf) {
            acc[mf][0] = __builtin_amdgcn_mfma_f32_16x16x32_bf16(afh[mf], bhR, acc[mf][0], 0, 0, 0);
            acc[mf][0] = __builtin_amdgcn_mfma_f32_16x16x32_bf16(afh[mf], blR, acc[mf][0], 0, 0, 0);
            acc[mf][0] = __builtin_amdgcn_mfma_f32_16x16x32_bf16(afl[mf], bhR, acc[mf][0], 0, 0, 0);
            acc[mf][1] = __builtin_amdgcn_mfma_f32_16x16x32_bf16(afh[mf], bhN, acc[mf][1], 0, 0, 0);
            acc[mf][1] = __builtin_amdgcn_mfma_f32_16x16x32_bf16(afh[mf], blN, acc[mf][1], 0, 0, 0);
            acc[mf][1] = __builtin_amdgcn_mfma_f32_16x16x32_bf16(afl[mf], bhN, acc[mf][1], 0, 0, 0);
        }

        // stage chunk kc+1 (converted from aP1, loaded a full iteration ago)
        if (kc + 1 < NCHUNK)
            CONVERT_STORE(nxt, aP1);

        __syncthreads();

        // rotate pipelines
        aP1 = aP2;
        bhR = bhRn; blR = blRn; bhN = bhNn; blN = blNn;
    }

    // ---- lane-local fuse: noisy = route + noise * softplus(noise_logit) ----
    // D layout: col = lane&15, row = quad*4 + r
    {
        int e = wid * 16 + n16;
        float brv = br[e], bnv = bn[e];
        #pragma unroll
        for (int mf = 0; mf < 2; ++mf)
            #pragma unroll
            for (int r = 0; r < 4; ++r) {
                int t = mf * 16 + quad * 4 + r;
                float nz    = noise[(size_t)(m0 + t) * NE + e];
                float route = acc[mf][0][r] + brv;
                float nl    = acc[mf][1][r] + bnv;
                Cs[t * CS_LD + e] = fmaf(nz, softplus_f(nl), route);
            }
    }
    __syncthreads();

    // ---- top-2 + softmax (one thread per token; in-order scan = stable ties) ----
    if (tid < M_TILE) {
        const int t = tid;
        float v1 = -INFINITY, v2 = -INFINITY;
        int e1 = 0, e2 = 0;
        #pragma unroll 8
        for (int e = 0; e < NE; ++e) {
            float v = Cs[t * CS_LD + e];
            if (v > v1) { v2 = v1; e2 = e1; v1 = v; e1 = e; }
            else if (v > v2) { v2 = v; e2 = e; }
        }
        float ex = expf(v2 - v1);
        float denom = 1.f + ex;
        s_p1[t] = 1.f / denom;
        s_p2[t] = ex / denom;
        s_e1[t] = e1;
        s_e2[t] = e2;
        float2 iv = make_float2((float)e1, (float)e2);
        *(float2*)(out + OUT_IDX_BASE + (size_t)(m0 + t) * 2) = iv;
    }
    __syncthreads();

    // ---- coalesced scatter of router_output [32 tokens x 64 experts] ----
    #pragma unroll
    for (int i = 0; i < 2; ++i) {
        int gi = i * 256 + tid;       // 0..511 float4s
        int t  = gi >> 4;
        int e0 = (gi & 15) * 4;
        float p1 = s_p1[t], p2 = s_p2[t];
        int   e1 = s_e1[t], e2 = s_e2[t];
        float4 v;
        v.x = (e0 + 0 == e1) ? p1 : ((e0 + 0 == e2) ? p2 : 0.f);
        v.y = (e0 + 1 == e1) ? p1 : ((e0 + 1 == e2) ? p2 : 0.f);
        v.z = (e0 + 2 == e1) ? p1 : ((e0 + 2 == e2) ? p2 : 0.f);
        v.w = (e0 + 3 == e1) ? p1 : ((e0 + 3 == e2) ? p2 : 0.f);
        *(float4*)(out + (size_t)(m0 + t) * NE + e0) = v;
    }
}

extern "C" void kernel_launch(void* const* d_in, const int* in_sizes, int n_in,
                              void* d_out, int out_size, void* d_ws, size_t ws_size,
                              hipStream_t stream) {
    const float* A     = (const float*)d_in[0];
    const float* noise = (const float*)d_in[1];
    const float* Wr    = (const float*)d_in[2];
    const float* br    = (const float*)d_in[3];
    const float* Wn    = (const float*)d_in[4];
    const float* bn    = (const float*)d_in[5];
    float* out = (float*)d_out;

    short* Bh = (short*)d_ws;
    short* Bl = Bh + W_ELEMS;

    prepack_w<<<dim3(W_ELEMS / 8 / 256), dim3(256), 0, stream>>>(Wr, Wn, Bh, Bl);
    router_mfma<<<dim3(T_TOKENS / M_TILE), dim3(256), 0, stream>>>(A, noise, br, bn, Bh, Bl, out);
}